// Round 9
// baseline (289.623 us; speedup 1.0000x reference)
//
#include <hip/hip_runtime.h>
#include <stdint.h>

#define DIM        10
#define WPTS       128                    // points per wave-chunk (2 per lane)
#define WFLOATS    (WPTS * DIM)           // 1280 floats per wave-chunk
#define WVECS      (WFLOATS / 4)          // 320 float4 per wave-chunk
#define WAVES      4                      // waves per block
#define THREADS    (WAVES * 64)           // 256
#define GRID       2048                   // 8192 waves (full capacity), 4 chunks each

typedef float f32x4 __attribute__((ext_vector_type(4)));

// Codebook as compile-time constant; fully-unrolled uses constant-fold.
static constexpr float CB[32][10] = {
 {-1,-1,-1,-1,-1,-1,-1,-1,-1,-1},{-1,-1,-1,-1,1,1,-1,-1,-1,1},{-1,-1,-1,1,-1,-1,-1,-1,1,1},{-1,-1,-1,1,1,1,-1,-1,1,-1},
 {-1,-1,1,-1,-1,-1,-1,1,1,-1},{-1,-1,1,-1,1,1,-1,1,1,1},{-1,-1,1,1,-1,-1,-1,1,-1,1},{-1,-1,1,1,1,1,-1,1,-1,-1},
 {-1,1,-1,-1,-1,-1,1,1,-1,-1},{-1,1,-1,-1,1,1,1,1,-1,1},{-1,1,-1,1,-1,-1,1,1,1,1},{-1,1,-1,1,1,1,1,1,1,-1},
 {-1,1,1,-1,-1,-1,1,-1,1,-1},{-1,1,1,-1,1,1,1,-1,1,1},{-1,1,1,1,-1,-1,1,-1,-1,1},{-1,1,1,1,1,1,1,-1,-1,-1},
 {1,-1,-1,-1,-1,1,1,-1,-1,-1},{1,-1,-1,-1,1,-1,1,-1,-1,1},{1,-1,-1,1,-1,1,1,-1,1,1},{1,-1,-1,1,1,-1,1,-1,1,-1},
 {1,-1,1,-1,-1,1,1,1,1,-1},{1,-1,1,-1,1,-1,1,1,1,1},{1,-1,1,1,-1,1,1,1,-1,1},{1,-1,1,1,1,-1,1,1,-1,-1},
 {1,1,-1,-1,-1,1,-1,1,-1,-1},{1,1,-1,-1,1,-1,-1,1,-1,1},{1,1,-1,1,-1,1,-1,1,1,1},{1,1,-1,1,1,-1,-1,1,1,-1},
 {1,1,1,-1,-1,1,-1,-1,1,-1},{1,1,1,-1,1,-1,-1,-1,1,1},{1,1,1,1,-1,1,-1,-1,-1,1},{1,1,1,1,1,-1,-1,-1,-1,-1}};

// 10-bit sign mask per codeword (bit j set iff CB[k][j] == +1).
struct CBMasks { uint32_t m[32]; };
static constexpr CBMasks make_masks() {
    CBMasks r{};
    for (int k = 0; k < 32; ++k) {
        uint32_t mm = 0;
        for (int j = 0; j < DIM; ++j)
            if (CB[k][j] > 0.0f) mm |= (1u << j);
        r.m[k] = mm;
    }
    return r;
}
static constexpr CBMasks CBM = make_masks();

// Per-point signed-correlation argmax. IDENTICAL summation order and
// strict-'>' tie rule as all passing kernels (bit-identical output).
__device__ __forceinline__ uint32_t argmax_mask(const float* __restrict__ x) {
    float    best = -1e30f;
    uint32_t bm   = 0u;                               // codeword 0 (all -1)
    #pragma unroll
    for (int k = 0; k < 32; ++k) {
        float s = 0.0f;
        #pragma unroll
        for (int j = 0; j < DIM; ++j)
            s = (CB[k][j] > 0.0f) ? (s + x[j]) : (s - x[j]);   // add/sub chain
        if (s > best) { best = s; bm = CBM.m[k]; }             // cmp + cndmask
    }
    return bm;
}

// Chunk buffer with NAMED fields -> guaranteed register residency.
struct Buf { float4 v0, v1, v2, v3, v4; };

__device__ __forceinline__ Buf load_chunk(const float4* __restrict__ g, int lane) {
    Buf b;
    b.v0 = g[lane];       b.v1 = g[lane +  64]; b.v2 = g[lane + 128];
    b.v3 = g[lane + 192]; b.v4 = g[lane + 256];
    return b;
}

// ZERO-runtime-cost ordering fence for same-wave LDS reuse.
// WHY (r7 post-mortem): the wave-private staging writes (bytes 16*lane+...)
// and the consume reads (bytes 80*lane+...) only alias ACROSS lanes, so the
// compiler's per-thread alias analysis may reorder them (it did in r7 ->
// absmax 2.0). Hardware executes a wave's DS ops in issue order, so pinning
// the compile-time order is sufficient — no s_barrier / waitcnt needed.
__device__ __forceinline__ void wave_order_fence() {
    __builtin_amdgcn_sched_barrier(0);     // no instr may cross (MIR sched)
    __builtin_amdgcn_wave_barrier();       // no-op instr, blocks memory motion
    __builtin_amdgcn_sched_barrier(0);
    asm volatile("" ::: "memory");         // IR-level fence
}

// One chunk: stage b -> wave-private LDS, refill b with chunk wpre (depth-2
// prefetch), compute both points, nontemporal coalesced store of chunk w.
// No barriers: own-wave LDS order is pinned by wave_order_fence; mask
// exchange is ds_bpermute (in-register cross-lane).
__device__ __forceinline__ void do_chunk(
    Buf& b, int w, int wpre, int totw, int lane,
    float* __restrict__ sW,
    const float4* __restrict__ gin, float* __restrict__ out)
{
    // ---- stage regs -> wave-private LDS (compiler waits vmcnt for b) ----
    float4* __restrict__ s4 = (float4*)sW;
    s4[lane]       = b.v0;  s4[lane +  64] = b.v1;  s4[lane + 128] = b.v2;
    s4[lane + 192] = b.v3;  s4[lane + 256] = b.v4;

    wave_order_fence();                    // (1) reads below stay below writes

    // ---- depth-2 prefetch: issue chunk w+2*stride now; lands ~2 full
    // iterations before consumption ----
    if (wpre < totw) b = load_chunk(gin + (size_t)wpre * WVECS, lane);

    // ---- read MY two points: 80 B contiguous = 5x ds_read_b128
    // (stride 80 B tiles all 32 banks across each 8-lane group) ----
    const float4* __restrict__ sp = (const float4*)(sW + lane * 2 * DIM);
    const float4 a0 = sp[0], a1 = sp[1], a2 = sp[2], a3 = sp[3], a4 = sp[4];

    wave_order_fence();                    // (2) next chunk's writes stay below

    float xA[DIM], xB[DIM];
    xA[0]=a0.x; xA[1]=a0.y; xA[2]=a0.z; xA[3]=a0.w;
    xA[4]=a1.x; xA[5]=a1.y; xA[6]=a1.z; xA[7]=a1.w;
    xA[8]=a2.x; xA[9]=a2.y;
    xB[0]=a2.z; xB[1]=a2.w;
    xB[2]=a3.x; xB[3]=a3.y; xB[4]=a3.z; xB[5]=a3.w;
    xB[6]=a4.x; xB[7]=a4.y; xB[8]=a4.z; xB[9]=a4.w;

    // ---- argmax both points; pack masks (pt 2*lane, 2*lane+1) ----
    const uint32_t pk = argmax_mask(xA) | (argmax_mask(xB) << DIM);

    // ---- epilogue: coalesced nontemporal dwordx4 stores; masks via
    // ds_bpermute. nt: write-once output stays out of L3 so the input
    // stays L3-resident (FETCH was 82MB of 168MB thanks to L3 hits). ----
    f32x4* __restrict__ gout = (f32x4*)out + (size_t)w * WVECS;
    #pragma unroll
    for (int q = 0; q < 5; ++q) {
        const int v  = q * 64 + lane;        // vec index in chunk [0,320)
        const int gg = 4 * v;                // first element of vec
        const int pA = gg / DIM;             // point 0..127 (magic-mul)
        const int cc = gg - pA * DIM;        // 0,2,4,6,8
        const int pB = (pA + 1 < WPTS) ? (pA + 1) : (WPTS - 1);
        const uint32_t pkA = (uint32_t)__builtin_amdgcn_ds_bpermute(
                                 (pA >> 1) << 2, (int)pk);
        const uint32_t pkB = (uint32_t)__builtin_amdgcn_ds_bpermute(
                                 (pB >> 1) << 2, (int)pk);
        const uint32_t A = (pkA >> ((pA & 1) * DIM)) & 0x3FFu;
        const uint32_t B = (pkB >> ((pB & 1) * DIM)) & 0x3FFu;
        const uint32_t mm = (A >> cc) | (B << (DIM - cc));    // splice
        f32x4 o;
        o.x = __uint_as_float(0xBF800000u ^ ((mm        & 1u) << 31));
        o.y = __uint_as_float(0xBF800000u ^ (((mm >> 1) & 1u) << 31));
        o.z = __uint_as_float(0xBF800000u ^ (((mm >> 2) & 1u) << 31));
        o.w = __uint_as_float(0xBF800000u ^ (((mm >> 3) & 1u) << 31));
        __builtin_nontemporal_store(o, gout + v);
    }
}

__global__ __launch_bounds__(THREADS) void softdec_kernel(
    const float* __restrict__ sig, float* __restrict__ out, int totw)
{
    __shared__ float sIn[WAVES][WFLOATS];       // 20 KiB, one 5-KiB slice/wave

    const int lane = threadIdx.x & 63;
    const int wv   = threadIdx.x >> 6;
    const int nw   = GRID * WAVES;              // 8192 waves
    float* __restrict__ sW = sIn[wv];
    const float4* __restrict__ gin = (const float4*)sig;

    int w = blockIdx.x * WAVES + wv;

    // ---- prologue: fill BOTH pipeline stages (10 KB in flight per wave) ----
    Buf A = load_chunk(gin + (size_t)w * WVECS, lane);
    Buf B;
    if (w + nw < totw) B = load_chunk(gin + (size_t)(w + nw) * WVECS, lane);

    // ---- steady state: 2-unrolled so A/B roles are compile-time static ----
    while (w < totw) {
        do_chunk(A, w, w + 2 * nw, totw, lane, sW, gin, out);
        w += nw;
        if (w >= totw) break;
        do_chunk(B, w, w + 2 * nw, totw, lane, sW, gin, out);
        w += nw;
    }
}

extern "C" void kernel_launch(void* const* d_in, const int* in_sizes, int n_in,
                              void* d_out, int out_size, void* d_ws, size_t ws_size,
                              hipStream_t stream) {
    const float* sig = (const float*)d_in[0];
    float* out = (float*)d_out;
    const int total = in_sizes[0];            // B*N*D = 41,943,040 floats
    const int pts   = total / DIM;            // 4,194,304 points
    const int totw  = pts / WPTS;             // 32,768 wave-chunks (exact)
    softdec_kernel<<<GRID, THREADS, 0, stream>>>(sig, out, totw);
}